// Round 4
// baseline (377.843 us; speedup 1.0000x reference)
//
#include <hip/hip_runtime.h>
#include <math.h>

#define N_C 1024
#define M_F 64
#define B_R 32768
#define R_B 32       // sample rows per block (2 m-tiles of 16)
#define LDX 132      // padded fp32 leading dim for X in LDS

typedef short bf16x8 __attribute__((ext_vector_type(8)));
typedef float f32x4 __attribute__((ext_vector_type(4)));

__device__ __forceinline__ short f2bf(float x) {
  unsigned b = __float_as_uint(x);
  b += 0x7fffu + ((b >> 16) & 1u);   // RTNE (finite inputs only)
  return (short)(b >> 16);
}
__device__ __forceinline__ float bf2f(short h) {
  return __uint_as_float(((unsigned)(unsigned short)h) << 16);
}

__global__ void logprior_kernel(const float* __restrict__ lm, float* __restrict__ lp) {
  __shared__ float red[256];
  const int t = threadIdx.x;
  float v[4];
  float mx = -INFINITY;
#pragma unroll
  for (int i = 0; i < 4; ++i) { v[i] = lm[i * 256 + t]; mx = fmaxf(mx, v[i]); }
  red[t] = mx;
  __syncthreads();
  for (int s = 128; s > 0; s >>= 1) {
    if (t < s) red[t] = fmaxf(red[t], red[t + s]);
    __syncthreads();
  }
  mx = red[0];
  __syncthreads();
  float sum = 0.f;
#pragma unroll
  for (int i = 0; i < 4; ++i) { v[i] -= mx; sum += expf(v[i]); }
  red[t] = sum;
  __syncthreads();
  for (int s = 128; s > 0; s >>= 1) {
    if (t < s) red[t] += red[t + s];
    __syncthreads();
  }
  const float l = logf(red[0]);
#pragma unroll
  for (int i = 0; i < 4; ++i) lp[i * 256 + t] = v[i] - l;
}

// Exact 3-way bf16 split of Y = [C | C^2], MFMA B-frag swizzled:
// blob[(s*64 + c)*64 + lane] holds Y[n = c*16+(lane&15)][k = s*32+(lane>>4)*8 ..+7]
__global__ void prep_y(const float* __restrict__ centroids,
                       bf16x8* __restrict__ yh, bf16x8* __restrict__ ym,
                       bf16x8* __restrict__ yl) {
  const int tid = blockIdx.x * 256 + threadIdx.x;  // 0..16383
  const int l = tid & 63;
  const int c = (tid >> 6) & 63;
  const int s = tid >> 12;
  const int n = c * 16 + (l & 15);
  const int k0 = s * 32 + (l >> 4) * 8;
  bf16x8 h, mid, lo;
#pragma unroll
  for (int j = 0; j < 8; ++j) {
    const int k = k0 + j;
    float y;
    if (k < 64) {
      y = centroids[n * M_F + k];
    } else {
      const float cc = centroids[n * M_F + (k - 64)];
      y = cc * cc;
    }
    const short hh = f2bf(y);
    const float r1 = y - bf2f(hh);        // exact
    const short mm = f2bf(r1);
    const float r2 = r1 - bf2f(mm);       // exact
    h[j] = hh;
    mid[j] = mm;
    lo[j] = f2bf(r2);                     // exact
  }
  const int blob = (s * 64 + c) * 64 + l;
  yh[blob] = h;
  ym[blob] = mid;
  yl[blob] = lo;
}

// 512 threads = 8 waves. Wave w: cols [w*128, w*128+128) (8 c-tiles),
// 2 m-tiles (rows 0-15, 16-31 of the block's 32 rows).
__global__ __launch_bounds__(512, 2) void rmm_main(
    const float* __restrict__ samples, const float* __restrict__ mask,
    const float* __restrict__ sd, const float* __restrict__ lp_g,
    const bf16x8* __restrict__ yh_g, const bf16x8* __restrict__ ym_g,
    const bf16x8* __restrict__ yl_g, float* __restrict__ out) {
  __shared__ float xs[R_B * LDX];   // X fp32 [row][k]: k<64 -> -2uA, k>=64 -> u
  __shared__ float lp_s[N_C];
  __shared__ float ad_s[R_B];
  __shared__ float red_s[R_B * 8];

  const int t = threadIdx.x;
  const int b0 = blockIdx.x * R_B;
  const int w = t >> 6;   // 0..7
  const int l = t & 63;
  const int m = l & 15;
  const int q = l >> 4;

  if (t < 256) *(float4*)(lp_s + (t << 2)) = *(const float4*)(lp_g + (t << 2));

  // ---- build X rows, A_d = sum((m*A)^2): 512 thr = 32 rows x 16 quads ----
  {
    const int r = t >> 4;             // 0..31
    const int j4 = (t & 15) << 2;
    const float4 s4 = *(const float4*)(samples + (size_t)(b0 + r) * M_F + j4);
    const float4 m4 = *(const float4*)(mask + (size_t)(b0 + r) * M_F + j4);
    const float4 d4 = *(const float4*)(sd + j4);
    const float sa[4] = {s4.x, s4.y, s4.z, s4.w};
    const float ma[4] = {m4.x, m4.y, m4.z, m4.w};
    const float da[4] = {d4.x, d4.y, d4.z, d4.w};
    float ad = 0.f;
#pragma unroll
    for (int k = 0; k < 4; ++k) {
      const float mm = ma[k] / da[k];
      const float uu = mm * mm;
      const float mA = mm * sa[k];
      ad = fmaf(mA, mA, ad);
      xs[r * LDX + j4 + k] = -2.0f * (uu * sa[k]);
      xs[r * LDX + 64 + j4 + k] = uu;
    }
#pragma unroll
    for (int off = 1; off < 16; off <<= 1) ad += __shfl_xor(ad, off, 64);
    if ((t & 15) == 0) ad_s[r] = ad;
  }

  f32x4 acc[2][8];
#pragma unroll
  for (int mt = 0; mt < 2; ++mt)
#pragma unroll
    for (int c = 0; c < 8; ++c) acc[mt][c] = (f32x4){0.f, 0.f, 0.f, 0.f};

  __syncthreads();

  // split order per accumulator (small -> large); index 0=h,1=m,2=l
  const int sx[8] = {1, 2, 0, 1, 2, 0, 1, 0};
  const int sy[8] = {2, 1, 2, 1, 0, 1, 0, 0};

  // ---- K loop: 4 steps of K=32 ----
#pragma unroll 1
  for (int s = 0; s < 4; ++s) {
    const size_t sbase = (size_t)(s * 64 + w * 8) * 64 + l;
    const bf16x8* yh = yh_g + sbase;
    const bf16x8* ym = ym_g + sbase;
    const bf16x8* yl = yl_g + sbase;

    // issue pair-0 loads first, then build A frags (covers L2 latency)
    bf16x8 B[3][2][2];   // [part][buf][tile]
#pragma unroll
    for (int tl = 0; tl < 2; ++tl) {
      B[0][0][tl] = yh[tl * 64];
      B[1][0][tl] = ym[tl * 64];
      B[2][0][tl] = yl[tl * 64];
    }

    bf16x8 A[3][2];      // [part][mt]
#pragma unroll
    for (int mt = 0; mt < 2; ++mt) {
      const float* xp = &xs[(mt * 16 + m) * LDX + s * 32 + q * 8];
      float av[8];
      *(float4*)&av[0] = *(const float4*)xp;
      *(float4*)&av[4] = *(const float4*)(xp + 4);
      bf16x8 ah, amd, alo;
#pragma unroll
      for (int j = 0; j < 8; ++j) {
        const short hh = f2bf(av[j]);
        const float r1 = av[j] - bf2f(hh);   // exact
        const short mm = f2bf(r1);
        const float r2 = r1 - bf2f(mm);      // exact
        ah[j] = hh;
        amd[j] = mm;
        alo[j] = f2bf(r2);                   // exact
      }
      A[0][mt] = ah;
      A[1][mt] = amd;
      A[2][mt] = alo;
    }

#pragma unroll
    for (int p = 0; p < 4; ++p) {
      const int cur = p & 1;
      const int nxt = cur ^ 1;
      if (p < 3) {
#pragma unroll
        for (int tl = 0; tl < 2; ++tl) {
          B[0][nxt][tl] = yh[(2 * (p + 1) + tl) * 64];
          B[1][nxt][tl] = ym[(2 * (p + 1) + tl) * 64];
          B[2][nxt][tl] = yl[(2 * (p + 1) + tl) * 64];
        }
      }
#pragma unroll
      for (int sp = 0; sp < 8; ++sp)
#pragma unroll
        for (int tl = 0; tl < 2; ++tl)
#pragma unroll
          for (int mt = 0; mt < 2; ++mt)
            acc[mt][2 * p + tl] = __builtin_amdgcn_mfma_f32_16x16x32_bf16(
                A[sx[sp]][mt], B[sy[sp]][cur][tl], acc[mt][2 * p + tl], 0, 0, 0);
    }
  }

  // ---- epilogue: C/D row = mt*16 + q*4+g, col = w*128 + c*16 + m ----
  float adv[2][4];
#pragma unroll
  for (int mt = 0; mt < 2; ++mt)
#pragma unroll
    for (int g = 0; g < 4; ++g) adv[mt][g] = ad_s[mt * 16 + q * 4 + g];
  float lpv[8];
#pragma unroll
  for (int c = 0; c < 8; ++c) lpv[c] = lp_s[w * 128 + c * 16 + m];

#pragma unroll
  for (int mt = 0; mt < 2; ++mt)
#pragma unroll
    for (int c = 0; c < 8; ++c)
#pragma unroll
      for (int g = 0; g < 4; ++g) {
        const float dist = fmaxf(adv[mt][g] + acc[mt][c][g], 0.0f);
        acc[mt][c][g] = lpv[c] - 0.5f * dist;
      }

  // row max (in-wave over m, then across 8 waves via LDS)
  float mx[2][4];
#pragma unroll
  for (int mt = 0; mt < 2; ++mt)
#pragma unroll
    for (int g = 0; g < 4; ++g) {
      float v = acc[mt][0][g];
#pragma unroll
      for (int c = 1; c < 8; ++c) v = fmaxf(v, acc[mt][c][g]);
#pragma unroll
      for (int off = 1; off < 16; off <<= 1) v = fmaxf(v, __shfl_xor(v, off, 64));
      mx[mt][g] = v;
    }
  if (m == 0) {
#pragma unroll
    for (int mt = 0; mt < 2; ++mt)
#pragma unroll
      for (int g = 0; g < 4; ++g) red_s[(mt * 16 + q * 4 + g) * 8 + w] = mx[mt][g];
  }
  __syncthreads();
#pragma unroll
  for (int mt = 0; mt < 2; ++mt)
#pragma unroll
    for (int g = 0; g < 4; ++g) {
      const int row = mt * 16 + q * 4 + g;
      const float4 r0 = *(const float4*)(&red_s[row * 8]);
      const float4 r1 = *(const float4*)(&red_s[row * 8 + 4]);
      mx[mt][g] = fmaxf(fmaxf(fmaxf(r0.x, r0.y), fmaxf(r0.z, r0.w)),
                        fmaxf(fmaxf(r1.x, r1.y), fmaxf(r1.z, r1.w)));
    }
  __syncthreads();

  // exp + sum
  float sm[2][4];
#pragma unroll
  for (int mt = 0; mt < 2; ++mt)
#pragma unroll
    for (int g = 0; g < 4; ++g) {
      float ssum = 0.f;
#pragma unroll
      for (int c = 0; c < 8; ++c) {
        const float e = expf(acc[mt][c][g] - mx[mt][g]);
        acc[mt][c][g] = e;
        ssum += e;
      }
#pragma unroll
      for (int off = 1; off < 16; off <<= 1) ssum += __shfl_xor(ssum, off, 64);
      sm[mt][g] = ssum;
    }
  if (m == 0) {
#pragma unroll
    for (int mt = 0; mt < 2; ++mt)
#pragma unroll
      for (int g = 0; g < 4; ++g) red_s[(mt * 16 + q * 4 + g) * 8 + w] = sm[mt][g];
  }
  __syncthreads();
#pragma unroll
  for (int mt = 0; mt < 2; ++mt)
#pragma unroll
    for (int g = 0; g < 4; ++g) {
      const int row = mt * 16 + q * 4 + g;
      const float4 r0 = *(const float4*)(&red_s[row * 8]);
      const float4 r1 = *(const float4*)(&red_s[row * 8 + 4]);
      sm[mt][g] = ((r0.x + r0.y) + (r0.z + r0.w)) + ((r1.x + r1.y) + (r1.z + r1.w));
    }
  __syncthreads();

  // pdf = e/S1 (IEEE div), thr = 0.05*fl(1/S1), truncated sum
  float thr[2][4], qs[2][4];
#pragma unroll
  for (int mt = 0; mt < 2; ++mt)
#pragma unroll
    for (int g = 0; g < 4; ++g) {
      const float S1 = sm[mt][g];
      thr[mt][g] = 0.05f * (1.0f / S1);
      float s2 = 0.f;
#pragma unroll
      for (int c = 0; c < 8; ++c) {
        const float p = acc[mt][c][g] / S1;   // IEEE div, matches np
        acc[mt][c][g] = p;
        s2 += (p > thr[mt][g]) ? p : 0.0f;
      }
#pragma unroll
      for (int off = 1; off < 16; off <<= 1) s2 += __shfl_xor(s2, off, 64);
      qs[mt][g] = s2;
    }
  if (m == 0) {
#pragma unroll
    for (int mt = 0; mt < 2; ++mt)
#pragma unroll
      for (int g = 0; g < 4; ++g) red_s[(mt * 16 + q * 4 + g) * 8 + w] = qs[mt][g];
  }
  __syncthreads();
#pragma unroll
  for (int mt = 0; mt < 2; ++mt)
#pragma unroll
    for (int g = 0; g < 4; ++g) {
      const int row = mt * 16 + q * 4 + g;
      const float4 r0 = *(const float4*)(&red_s[row * 8]);
      const float4 r1 = *(const float4*)(&red_s[row * 8 + 4]);
      qs[mt][g] = ((r0.x + r0.y) + (r0.z + r0.w)) + ((r1.x + r1.y) + (r1.z + r1.w));
    }

  const size_t colbase = (size_t)(w * 128 + m);
#pragma unroll
  for (int mt = 0; mt < 2; ++mt)
#pragma unroll
    for (int g = 0; g < 4; ++g) {
      float* orow = out + (size_t)(b0 + mt * 16 + q * 4 + g) * N_C + colbase;
      float* lrow = orow + (size_t)B_R * N_C;
#pragma unroll
      for (int c = 0; c < 8; ++c) {
        const float p = acc[mt][c][g];
        const float pf = (p > thr[mt][g]) ? (p / qs[mt][g]) : 0.0f;
        orow[c * 16] = pf;
        lrow[c * 16] = logf(pf + 1e-20f);
      }
    }
}

extern "C" void kernel_launch(void* const* d_in, const int* in_sizes, int n_in,
                              void* d_out, int out_size, void* d_ws, size_t ws_size,
                              hipStream_t stream) {
  const float* samples   = (const float*)d_in[0];
  const float* mask      = (const float*)d_in[1];
  const float* centroids = (const float*)d_in[2];
  const float* sd        = (const float*)d_in[3];
  const float* lm        = (const float*)d_in[4];
  float* out = (float*)d_out;

  char* ws = (char*)d_ws;
  float* lp  = (float*)ws;                          // 4 KB
  bf16x8* yh = (bf16x8*)(ws + 4096);                // 256 KB
  bf16x8* ym = (bf16x8*)(ws + 4096 + 262144);       // 256 KB
  bf16x8* yl = (bf16x8*)(ws + 4096 + 2 * 262144);   // 256 KB

  logprior_kernel<<<1, 256, 0, stream>>>(lm, lp);
  prep_y<<<64, 256, 0, stream>>>(centroids, yh, ym, yl);
  rmm_main<<<B_R / R_B, 512, 0, stream>>>(samples, mask, sd, lp, yh, ym, yl, out);
}

// Round 5
// 357.980 us; speedup vs baseline: 1.0555x; 1.0555x over previous
//
#include <hip/hip_runtime.h>
#include <math.h>

#define N_C 1024
#define M_F 64
#define B_R 32768
#define R_B 16       // sample rows per block
#define LDX 132      // padded fp32 leading dim for X in LDS

typedef short bf16x8 __attribute__((ext_vector_type(8)));
typedef float f32x4 __attribute__((ext_vector_type(4)));
typedef unsigned int uint4v __attribute__((ext_vector_type(4)));

// Exact truncation-based 3-way split of 8 fp32 into 3 bf16x8 (h+m+l == x exactly).
// Truncation (round-to-zero at 16 bits) keeps residuals exact; no RTNE needed since
// the split only has to be self-consistent, not match any external convention.
__device__ __forceinline__ void split3(const float* f, bf16x8& h, bf16x8& m, bf16x8& l) {
  uint4v hp, mp, lp;
#pragma unroll
  for (int i = 0; i < 4; ++i) {
    const unsigned b0 = __float_as_uint(f[2 * i]);
    const unsigned b1 = __float_as_uint(f[2 * i + 1]);
    const unsigned h0 = b0 & 0xFFFF0000u, h1 = b1 & 0xFFFF0000u;
    const float r0 = f[2 * i] - __uint_as_float(h0);       // exact
    const float r1 = f[2 * i + 1] - __uint_as_float(h1);   // exact
    hp[i] = (b0 >> 16) | h1;
    const unsigned rb0 = __float_as_uint(r0), rb1 = __float_as_uint(r1);
    const unsigned m0 = rb0 & 0xFFFF0000u, m1 = rb1 & 0xFFFF0000u;
    const float s0 = r0 - __uint_as_float(m0);             // exact
    const float s1 = r1 - __uint_as_float(m1);             // exact
    mp[i] = (rb0 >> 16) | m1;
    lp[i] = (__float_as_uint(s0) >> 16) | (__float_as_uint(s1) & 0xFFFF0000u);
  }
  h = __builtin_bit_cast(bf16x8, hp);
  m = __builtin_bit_cast(bf16x8, mp);
  l = __builtin_bit_cast(bf16x8, lp);
}

__global__ void logprior_kernel(const float* __restrict__ lm, float* __restrict__ lp) {
  __shared__ float red[256];
  const int t = threadIdx.x;
  float v[4];
  float mx = -INFINITY;
#pragma unroll
  for (int i = 0; i < 4; ++i) { v[i] = lm[i * 256 + t]; mx = fmaxf(mx, v[i]); }
  red[t] = mx;
  __syncthreads();
  for (int s = 128; s > 0; s >>= 1) {
    if (t < s) red[t] = fmaxf(red[t], red[t + s]);
    __syncthreads();
  }
  mx = red[0];
  __syncthreads();
  float sum = 0.f;
#pragma unroll
  for (int i = 0; i < 4; ++i) { v[i] -= mx; sum += expf(v[i]); }
  red[t] = sum;
  __syncthreads();
  for (int s = 128; s > 0; s >>= 1) {
    if (t < s) red[t] += red[t + s];
    __syncthreads();
  }
  const float l = logf(red[0]);
#pragma unroll
  for (int i = 0; i < 4; ++i) lp[i * 256 + t] = v[i] - l;
}

// Y = [C | C^2] fp32, MFMA B-frag swizzled:
// yf[((s*64 + c)*64 + lane)*8 + j] = Y[n = c*16+(lane&15)][k = s*32+(lane>>4)*8+j]
__global__ void prep_yf(const float* __restrict__ centroids, float* __restrict__ yf) {
  const int tid = blockIdx.x * 256 + threadIdx.x;  // 0..16383
  const int l = tid & 63;
  const int c = (tid >> 6) & 63;
  const int s = tid >> 12;
  const int n = c * 16 + (l & 15);
  const int k0 = s * 32 + (l >> 4) * 8;
  float v[8];
#pragma unroll
  for (int j = 0; j < 8; ++j) {
    const int k = k0 + j;
    if (k < 64) {
      v[j] = centroids[n * M_F + k];
    } else {
      const float cc = centroids[n * M_F + (k - 64)];
      v[j] = cc * cc;
    }
  }
  float* dst = yf + (size_t)tid * 8;
  *(float4*)dst = *(const float4*)&v[0];
  *(float4*)(dst + 4) = *(const float4*)&v[4];
}

__global__ __launch_bounds__(256, 3) void rmm_main(
    const float* __restrict__ samples, const float* __restrict__ mask,
    const float* __restrict__ sd, const float* __restrict__ lp_g,
    const float* __restrict__ yf_g, float* __restrict__ out) {
  __shared__ float xs[R_B * LDX];   // X fp32 [row][k]: k<64 -> -2uA, k>=64 -> u
  __shared__ float lp_s[N_C];
  __shared__ float ad_s[R_B];
  __shared__ float red_s[R_B * 4];

  const int t = threadIdx.x;
  const int b0 = blockIdx.x * R_B;
  const int w = t >> 6;   // wave id: cols [w*256, w*256+256) -> c-tiles w*16..w*16+15
  const int l = t & 63;
  const int m = l & 15;
  const int q = l >> 4;

  *(float4*)(lp_s + (t << 2)) = *(const float4*)(lp_g + (t << 2));

  // ---- build X rows, A_d = sum((m*A)^2) ----
  {
    const int r = t >> 4;
    const int j4 = (t & 15) << 2;
    const float4 s4 = *(const float4*)(samples + (size_t)(b0 + r) * M_F + j4);
    const float4 m4 = *(const float4*)(mask + (size_t)(b0 + r) * M_F + j4);
    const float4 d4 = *(const float4*)(sd + j4);
    const float sa[4] = {s4.x, s4.y, s4.z, s4.w};
    const float ma[4] = {m4.x, m4.y, m4.z, m4.w};
    const float da[4] = {d4.x, d4.y, d4.z, d4.w};
    float ad = 0.f;
#pragma unroll
    for (int k = 0; k < 4; ++k) {
      const float mm = ma[k] / da[k];
      const float uu = mm * mm;
      const float mA = mm * sa[k];
      ad = fmaf(mA, mA, ad);
      xs[r * LDX + j4 + k] = -2.0f * (uu * sa[k]);
      xs[r * LDX + 64 + j4 + k] = uu;
    }
#pragma unroll
    for (int off = 1; off < 16; off <<= 1) ad += __shfl_xor(ad, off, 64);
    if ((t & 15) == 0) ad_s[r] = ad;
  }

  f32x4 acc[16];
#pragma unroll
  for (int c = 0; c < 16; ++c) acc[c] = (f32x4){0.f, 0.f, 0.f, 0.f};

  __syncthreads();

  // ---- K loop: 4 steps of K=32, fp32 B tiles split in-kernel (exact) ----
#pragma unroll 1
  for (int s = 0; s < 4; ++s) {
    // A fragment split (from LDS)
    const float* xp = &xs[m * LDX + s * 32 + q * 8];
    float av[8];
    *(float4*)&av[0] = *(const float4*)xp;
    *(float4*)&av[4] = *(const float4*)(xp + 4);
    bf16x8 ah, am, al;
    split3(av, ah, am, al);

    const float* yf = yf_g + ((size_t)(s * 64 + w * 16) * 64 + l) * 8;

    float F[2][8];
    *(float4*)&F[0][0] = *(const float4*)(yf);
    *(float4*)&F[0][4] = *(const float4*)(yf + 4);

#pragma unroll
    for (int c = 0; c < 16; ++c) {
      const int cur = c & 1;
      if (c < 15) {
        const float* nxt = yf + (size_t)(c + 1) * 512;
        *(float4*)&F[cur ^ 1][0] = *(const float4*)(nxt);
        *(float4*)&F[cur ^ 1][4] = *(const float4*)(nxt + 4);
      }
      bf16x8 bh, bm, bl;
      split3(F[cur], bh, bm, bl);
      // small -> large; only Xl*Yl dropped (~2^-30 rel per term)
      acc[c] = __builtin_amdgcn_mfma_f32_16x16x32_bf16(am, bl, acc[c], 0, 0, 0);
      acc[c] = __builtin_amdgcn_mfma_f32_16x16x32_bf16(al, bm, acc[c], 0, 0, 0);
      acc[c] = __builtin_amdgcn_mfma_f32_16x16x32_bf16(ah, bl, acc[c], 0, 0, 0);
      acc[c] = __builtin_amdgcn_mfma_f32_16x16x32_bf16(am, bm, acc[c], 0, 0, 0);
      acc[c] = __builtin_amdgcn_mfma_f32_16x16x32_bf16(al, bh, acc[c], 0, 0, 0);
      acc[c] = __builtin_amdgcn_mfma_f32_16x16x32_bf16(ah, bm, acc[c], 0, 0, 0);
      acc[c] = __builtin_amdgcn_mfma_f32_16x16x32_bf16(am, bh, acc[c], 0, 0, 0);
      acc[c] = __builtin_amdgcn_mfma_f32_16x16x32_bf16(ah, bh, acc[c], 0, 0, 0);
    }
  }

  // ---- epilogue: C/D layout row = q*4+g, col = w*256 + c*16 + m ----
  float adv[4];
#pragma unroll
  for (int g = 0; g < 4; ++g) adv[g] = ad_s[q * 4 + g];
  float lpv[16];
#pragma unroll
  for (int c = 0; c < 16; ++c) lpv[c] = lp_s[w * 256 + c * 16 + m];

#pragma unroll
  for (int c = 0; c < 16; ++c)
#pragma unroll
    for (int g = 0; g < 4; ++g) {
      const float dist = fmaxf(adv[g] + acc[c][g], 0.0f);
      acc[c][g] = lpv[c] - 0.5f * dist;
    }

  float mx[4];
#pragma unroll
  for (int g = 0; g < 4; ++g) {
    float v = acc[0][g];
#pragma unroll
    for (int c = 1; c < 16; ++c) v = fmaxf(v, acc[c][g]);
#pragma unroll
    for (int off = 1; off < 16; off <<= 1) v = fmaxf(v, __shfl_xor(v, off, 64));
    mx[g] = v;
  }
  if (m == 0) {
#pragma unroll
    for (int g = 0; g < 4; ++g) red_s[(q * 4 + g) * 4 + w] = mx[g];
  }
  __syncthreads();
#pragma unroll
  for (int g = 0; g < 4; ++g) {
    const float4 rv = *(const float4*)(&red_s[(q * 4 + g) * 4]);
    mx[g] = fmaxf(fmaxf(rv.x, rv.y), fmaxf(rv.z, rv.w));
  }
  __syncthreads();

  float sm[4];
#pragma unroll
  for (int g = 0; g < 4; ++g) {
    float ssum = 0.f;
#pragma unroll
    for (int c = 0; c < 16; ++c) {
      const float e = __expf(acc[c][g] - mx[g]);   // v_exp_f32 path
      acc[c][g] = e;
      ssum += e;
    }
#pragma unroll
    for (int off = 1; off < 16; off <<= 1) ssum += __shfl_xor(ssum, off, 64);
    sm[g] = ssum;
  }
  if (m == 0) {
#pragma unroll
    for (int g = 0; g < 4; ++g) red_s[(q * 4 + g) * 4 + w] = sm[g];
  }
  __syncthreads();
#pragma unroll
  for (int g = 0; g < 4; ++g) {
    const float4 rv = *(const float4*)(&red_s[(q * 4 + g) * 4]);
    sm[g] = (rv.x + rv.y) + (rv.z + rv.w);
  }
  __syncthreads();

  // p = e/S1 (IEEE div -> tight truncation band), thr = 0.05*fl(1/S1)
  float thr[4], qs[4];
#pragma unroll
  for (int g = 0; g < 4; ++g) {
    const float S1 = sm[g];
    thr[g] = 0.05f * (1.0f / S1);
    float s2 = 0.f;
#pragma unroll
    for (int c = 0; c < 16; ++c) {
      const float p = acc[c][g] / S1;
      acc[c][g] = p;
      s2 += (p > thr[g]) ? p : 0.0f;
    }
#pragma unroll
    for (int off = 1; off < 16; off <<= 1) s2 += __shfl_xor(s2, off, 64);
    qs[g] = s2;
  }
  if (m == 0) {
#pragma unroll
    for (int g = 0; g < 4; ++g) red_s[(q * 4 + g) * 4 + w] = qs[g];
  }
  __syncthreads();
#pragma unroll
  for (int g = 0; g < 4; ++g) {
    const float4 rv = *(const float4*)(&red_s[(q * 4 + g) * 4]);
    qs[g] = (rv.x + rv.y) + (rv.z + rv.w);
  }

  const size_t colbase = (size_t)(w * 256 + m);
#pragma unroll
  for (int g = 0; g < 4; ++g) {
    const float rq = 1.0f / qs[g];
    float* orow = out + (size_t)(b0 + q * 4 + g) * N_C + colbase;
    float* lrow = orow + (size_t)B_R * N_C;
#pragma unroll
    for (int c = 0; c < 16; ++c) {
      const float p = acc[c][g];
      const float pf = (p > thr[g]) ? (p * rq) : 0.0f;   // pdf: 0.92 abs threshold, mul ok
      orow[c * 16] = pf;
      lrow[c * 16] = __logf(pf + 1e-20f);                // v_log_f32 path, err ~1e-5 << 0.92
    }
  }
}

extern "C" void kernel_launch(void* const* d_in, const int* in_sizes, int n_in,
                              void* d_out, int out_size, void* d_ws, size_t ws_size,
                              hipStream_t stream) {
  const float* samples   = (const float*)d_in[0];
  const float* mask      = (const float*)d_in[1];
  const float* centroids = (const float*)d_in[2];
  const float* sd        = (const float*)d_in[3];
  const float* lm        = (const float*)d_in[4];
  float* out = (float*)d_out;

  char* ws = (char*)d_ws;
  float* lp = (float*)ws;              // 4 KB
  float* yf = (float*)(ws + 4096);     // 512 KB fp32 Y blob

  logprior_kernel<<<1, 256, 0, stream>>>(lm, lp);
  prep_yf<<<64, 256, 0, stream>>>(centroids, yf);
  rmm_main<<<B_R / R_B, 256, 0, stream>>>(samples, mask, sd, lp, yf, out);
}

// Round 6
// 335.125 us; speedup vs baseline: 1.1275x; 1.0682x over previous
//
#include <hip/hip_runtime.h>
#include <math.h>

#define N_C 1024
#define M_F 64
#define B_R 32768
#define R_B 32       // sample rows per block (2 m-tiles of 16)
#define LDX 132      // padded fp32 leading dim for X in LDS

typedef short bf16x8 __attribute__((ext_vector_type(8)));
typedef float f32x4 __attribute__((ext_vector_type(4)));
typedef unsigned int uint4v __attribute__((ext_vector_type(4)));

__device__ __forceinline__ short f2bf(float x) {
  unsigned b = __float_as_uint(x);
  b += 0x7fffu + ((b >> 16) & 1u);   // RTNE (finite inputs only)
  return (short)(b >> 16);
}
__device__ __forceinline__ float bf2f(short h) {
  return __uint_as_float(((unsigned)(unsigned short)h) << 16);
}

// Exact truncation-based 3-way split (h+m+l == x exactly); bit-ops only.
__device__ __forceinline__ void split3(const float* f, bf16x8& h, bf16x8& m, bf16x8& l) {
  uint4v hp, mp, lp;
#pragma unroll
  for (int i = 0; i < 4; ++i) {
    const unsigned b0 = __float_as_uint(f[2 * i]);
    const unsigned b1 = __float_as_uint(f[2 * i + 1]);
    const unsigned h0 = b0 & 0xFFFF0000u, h1 = b1 & 0xFFFF0000u;
    const float r0 = f[2 * i] - __uint_as_float(h0);       // exact
    const float r1 = f[2 * i + 1] - __uint_as_float(h1);   // exact
    hp[i] = (b0 >> 16) | h1;
    const unsigned rb0 = __float_as_uint(r0), rb1 = __float_as_uint(r1);
    const unsigned m0 = rb0 & 0xFFFF0000u, m1 = rb1 & 0xFFFF0000u;
    const float s0 = r0 - __uint_as_float(m0);             // exact
    const float s1 = r1 - __uint_as_float(m1);             // exact
    mp[i] = (rb0 >> 16) | m1;
    lp[i] = (__float_as_uint(s0) >> 16) | (__float_as_uint(s1) & 0xFFFF0000u);
  }
  h = __builtin_bit_cast(bf16x8, hp);
  m = __builtin_bit_cast(bf16x8, mp);
  l = __builtin_bit_cast(bf16x8, lp);
}

__global__ void logprior_kernel(const float* __restrict__ lm, float* __restrict__ lp) {
  __shared__ float red[256];
  const int t = threadIdx.x;
  float v[4];
  float mx = -INFINITY;
#pragma unroll
  for (int i = 0; i < 4; ++i) { v[i] = lm[i * 256 + t]; mx = fmaxf(mx, v[i]); }
  red[t] = mx;
  __syncthreads();
  for (int s = 128; s > 0; s >>= 1) {
    if (t < s) red[t] = fmaxf(red[t], red[t + s]);
    __syncthreads();
  }
  mx = red[0];
  __syncthreads();
  float sum = 0.f;
#pragma unroll
  for (int i = 0; i < 4; ++i) { v[i] -= mx; sum += expf(v[i]); }
  red[t] = sum;
  __syncthreads();
  for (int s = 128; s > 0; s >>= 1) {
    if (t < s) red[t] += red[t + s];
    __syncthreads();
  }
  const float l = logf(red[0]);
#pragma unroll
  for (int i = 0; i < 4; ++i) lp[i * 256 + t] = v[i] - l;
}

// Exact 3-way bf16 split of Y = [C | C^2], MFMA B-frag swizzled:
// blob[(s*64 + c)*64 + lane] holds Y[n = c*16+(lane&15)][k = s*32+(lane>>4)*8 ..+7]
__global__ void prep_y(const float* __restrict__ centroids,
                       bf16x8* __restrict__ yh, bf16x8* __restrict__ ym,
                       bf16x8* __restrict__ yl) {
  const int tid = blockIdx.x * 256 + threadIdx.x;  // 0..16383
  const int l = tid & 63;
  const int c = (tid >> 6) & 63;
  const int s = tid >> 12;
  const int n = c * 16 + (l & 15);
  const int k0 = s * 32 + (l >> 4) * 8;
  bf16x8 h, mid, lo;
#pragma unroll
  for (int j = 0; j < 8; ++j) {
    const int k = k0 + j;
    float y;
    if (k < 64) {
      y = centroids[n * M_F + k];
    } else {
      const float cc = centroids[n * M_F + (k - 64)];
      y = cc * cc;
    }
    const short hh = f2bf(y);
    const float r1 = y - bf2f(hh);        // exact
    const short mm = f2bf(r1);
    const float r2 = r1 - bf2f(mm);       // exact
    h[j] = hh;
    mid[j] = mm;
    lo[j] = f2bf(r2);                     // exact
  }
  const int blob = (s * 64 + c) * 64 + l;
  yh[blob] = h;
  ym[blob] = mid;
  yl[blob] = lo;
}

// 256 threads = 4 waves. Wave w: c-tiles w*16..w*16+15 (cols w*256..+255),
// 2 m-tiles (rows 0-15, 16-31). 1024 blocks.
__global__ __launch_bounds__(256, 2) void rmm_main(
    const float* __restrict__ samples, const float* __restrict__ mask,
    const float* __restrict__ sd, const float* __restrict__ lp_g,
    const bf16x8* __restrict__ yh_g, const bf16x8* __restrict__ ym_g,
    const bf16x8* __restrict__ yl_g, float* __restrict__ out) {
  __shared__ float xs[R_B * LDX];   // X fp32 [row][k]: k<64 -> -2uA, k>=64 -> u
  __shared__ float lp_s[N_C];
  __shared__ float ad_s[R_B];
  __shared__ float red_s[R_B * 4];

  const int t = threadIdx.x;
  const int b0 = blockIdx.x * R_B;
  const int w = t >> 6;
  const int l = t & 63;
  const int m = l & 15;
  const int q = l >> 4;

  *(float4*)(lp_s + (t << 2)) = *(const float4*)(lp_g + (t << 2));

  // ---- build X rows, A_d: 256 thr = 32 rows x 8 lanes x 8 features ----
  {
    const int r = t >> 3;             // 0..31
    const int j8 = (t & 7) << 3;
    const float* sp = samples + (size_t)(b0 + r) * M_F + j8;
    const float* mp = mask + (size_t)(b0 + r) * M_F + j8;
    float sa[8], ma[8], da[8];
    *(float4*)&sa[0] = *(const float4*)sp;
    *(float4*)&sa[4] = *(const float4*)(sp + 4);
    *(float4*)&ma[0] = *(const float4*)mp;
    *(float4*)&ma[4] = *(const float4*)(mp + 4);
    *(float4*)&da[0] = *(const float4*)(sd + j8);
    *(float4*)&da[4] = *(const float4*)(sd + j8 + 4);
    float ad = 0.f;
#pragma unroll
    for (int k = 0; k < 8; ++k) {
      const float mm = ma[k] / da[k];
      const float uu = mm * mm;
      const float mA = mm * sa[k];
      ad = fmaf(mA, mA, ad);
      xs[r * LDX + j8 + k] = -2.0f * (uu * sa[k]);
      xs[r * LDX + 64 + j8 + k] = uu;
    }
#pragma unroll
    for (int off = 1; off < 8; off <<= 1) ad += __shfl_xor(ad, off, 64);
    if ((t & 7) == 0) ad_s[r] = ad;
  }

  f32x4 acc[2][16];
#pragma unroll
  for (int mt = 0; mt < 2; ++mt)
#pragma unroll
    for (int c = 0; c < 16; ++c) acc[mt][c] = (f32x4){0.f, 0.f, 0.f, 0.f};

  __syncthreads();

  // split order per accumulator (small -> large); 0=h,1=m,2=l
  const int sx[8] = {1, 2, 0, 1, 2, 0, 1, 0};
  const int sy[8] = {2, 1, 2, 1, 0, 1, 0, 0};

  // ---- K loop: 4 steps of K=32 ----
#pragma unroll 1
  for (int s = 0; s < 4; ++s) {
    const size_t sbase = (size_t)(s * 64 + w * 16) * 64 + l;
    const bf16x8* yh = yh_g + sbase;
    const bf16x8* ym = ym_g + sbase;
    const bf16x8* yl = yl_g + sbase;

    // issue first B loads, then build A frags (covers L2 latency)
    bf16x8 Bh[2], Bm[2], Bl[2];
#pragma unroll
    for (int p = 0; p < 2; ++p) {
      Bh[p] = yh[p * 64];
      Bm[p] = ym[p * 64];
      Bl[p] = yl[p * 64];
    }

    bf16x8 A[3][2];
#pragma unroll
    for (int mt = 0; mt < 2; ++mt) {
      const float* xp = &xs[(mt * 16 + m) * LDX + s * 32 + q * 8];
      float av[8];
      *(float4*)&av[0] = *(const float4*)xp;
      *(float4*)&av[4] = *(const float4*)(xp + 4);
      split3(av, A[0][mt], A[1][mt], A[2][mt]);
    }

#pragma unroll
    for (int c = 0; c < 16; ++c) {
      const int cur = c & 1;
      const bf16x8 bh = Bh[cur], bm = Bm[cur], bl = Bl[cur];
      if (c < 14) {
        Bh[cur] = yh[(c + 2) * 64];
        Bm[cur] = ym[(c + 2) * 64];
        Bl[cur] = yl[(c + 2) * 64];
      }
#pragma unroll
      for (int sp = 0; sp < 8; ++sp) {
        const bf16x8 bb = (sy[sp] == 0) ? bh : ((sy[sp] == 1) ? bm : bl);
#pragma unroll
        for (int mt = 0; mt < 2; ++mt)
          acc[mt][c] = __builtin_amdgcn_mfma_f32_16x16x32_bf16(
              A[sx[sp]][mt], bb, acc[mt][c], 0, 0, 0);
      }
    }
  }

  // ---- epilogue: C/D row = mt*16 + q*4+g, col = w*256 + c*16 + m ----
  float adv[2][4];
#pragma unroll
  for (int mt = 0; mt < 2; ++mt)
#pragma unroll
    for (int g = 0; g < 4; ++g) adv[mt][g] = ad_s[mt * 16 + q * 4 + g];
  float lpv[16];
#pragma unroll
  for (int c = 0; c < 16; ++c) lpv[c] = lp_s[w * 256 + c * 16 + m];

#pragma unroll
  for (int mt = 0; mt < 2; ++mt)
#pragma unroll
    for (int c = 0; c < 16; ++c)
#pragma unroll
      for (int g = 0; g < 4; ++g) {
        const float dist = fmaxf(adv[mt][g] + acc[mt][c][g], 0.0f);
        acc[mt][c][g] = lpv[c] - 0.5f * dist;
      }

  float mx[2][4];
#pragma unroll
  for (int mt = 0; mt < 2; ++mt)
#pragma unroll
    for (int g = 0; g < 4; ++g) {
      float v = acc[mt][0][g];
#pragma unroll
      for (int c = 1; c < 16; ++c) v = fmaxf(v, acc[mt][c][g]);
#pragma unroll
      for (int off = 1; off < 16; off <<= 1) v = fmaxf(v, __shfl_xor(v, off, 64));
      mx[mt][g] = v;
    }
  if (m == 0) {
#pragma unroll
    for (int mt = 0; mt < 2; ++mt)
#pragma unroll
      for (int g = 0; g < 4; ++g) red_s[(mt * 16 + q * 4 + g) * 4 + w] = mx[mt][g];
  }
  __syncthreads();
#pragma unroll
  for (int mt = 0; mt < 2; ++mt)
#pragma unroll
    for (int g = 0; g < 4; ++g) {
      const float4 rv = *(const float4*)(&red_s[(mt * 16 + q * 4 + g) * 4]);
      mx[mt][g] = fmaxf(fmaxf(rv.x, rv.y), fmaxf(rv.z, rv.w));
    }
  __syncthreads();

  float sm[2][4];
#pragma unroll
  for (int mt = 0; mt < 2; ++mt)
#pragma unroll
    for (int g = 0; g < 4; ++g) {
      float ssum = 0.f;
#pragma unroll
      for (int c = 0; c < 16; ++c) {
        const float e = __expf(acc[mt][c][g] - mx[mt][g]);
        acc[mt][c][g] = e;
        ssum += e;
      }
#pragma unroll
      for (int off = 1; off < 16; off <<= 1) ssum += __shfl_xor(ssum, off, 64);
      sm[mt][g] = ssum;
    }
  if (m == 0) {
#pragma unroll
    for (int mt = 0; mt < 2; ++mt)
#pragma unroll
      for (int g = 0; g < 4; ++g) red_s[(mt * 16 + q * 4 + g) * 4 + w] = sm[mt][g];
  }
  __syncthreads();
#pragma unroll
  for (int mt = 0; mt < 2; ++mt)
#pragma unroll
    for (int g = 0; g < 4; ++g) {
      const float4 rv = *(const float4*)(&red_s[(mt * 16 + q * 4 + g) * 4]);
      sm[mt][g] = (rv.x + rv.y) + (rv.z + rv.w);
    }
  __syncthreads();

  float thr[2][4], qs[2][4];
#pragma unroll
  for (int mt = 0; mt < 2; ++mt)
#pragma unroll
    for (int g = 0; g < 4; ++g) {
      const float S1 = sm[mt][g];
      thr[mt][g] = 0.05f * (1.0f / S1);
      float s2 = 0.f;
#pragma unroll
      for (int c = 0; c < 16; ++c) {
        const float p = acc[mt][c][g] / S1;   // IEEE div, matches np decision band
        acc[mt][c][g] = p;
        s2 += (p > thr[mt][g]) ? p : 0.0f;
      }
#pragma unroll
      for (int off = 1; off < 16; off <<= 1) s2 += __shfl_xor(s2, off, 64);
      qs[mt][g] = s2;
    }
  if (m == 0) {
#pragma unroll
    for (int mt = 0; mt < 2; ++mt)
#pragma unroll
      for (int g = 0; g < 4; ++g) red_s[(mt * 16 + q * 4 + g) * 4 + w] = qs[mt][g];
  }
  __syncthreads();
#pragma unroll
  for (int mt = 0; mt < 2; ++mt)
#pragma unroll
    for (int g = 0; g < 4; ++g) {
      const float4 rv = *(const float4*)(&red_s[(mt * 16 + q * 4 + g) * 4]);
      qs[mt][g] = (rv.x + rv.y) + (rv.z + rv.w);
    }

  const size_t colbase = (size_t)(w * 256 + m);
#pragma unroll
  for (int mt = 0; mt < 2; ++mt)
#pragma unroll
    for (int g = 0; g < 4; ++g) {
      const float rq = 1.0f / qs[mt][g];
      float* orow = out + (size_t)(b0 + mt * 16 + q * 4 + g) * N_C + colbase;
      float* lrow = orow + (size_t)B_R * N_C;
#pragma unroll
      for (int c = 0; c < 16; ++c) {
        const float p = acc[mt][c][g];
        const float pf = (p > thr[mt][g]) ? (p * rq) : 0.0f;
        orow[c * 16] = pf;
        lrow[c * 16] = __logf(pf + 1e-20f);
      }
    }
}

extern "C" void kernel_launch(void* const* d_in, const int* in_sizes, int n_in,
                              void* d_out, int out_size, void* d_ws, size_t ws_size,
                              hipStream_t stream) {
  const float* samples   = (const float*)d_in[0];
  const float* mask      = (const float*)d_in[1];
  const float* centroids = (const float*)d_in[2];
  const float* sd        = (const float*)d_in[3];
  const float* lm        = (const float*)d_in[4];
  float* out = (float*)d_out;

  char* ws = (char*)d_ws;
  float* lp  = (float*)ws;                          // 4 KB
  bf16x8* yh = (bf16x8*)(ws + 4096);                // 256 KB
  bf16x8* ym = (bf16x8*)(ws + 4096 + 262144);       // 256 KB
  bf16x8* yl = (bf16x8*)(ws + 4096 + 2 * 262144);   // 256 KB

  logprior_kernel<<<1, 256, 0, stream>>>(lm, lp);
  prep_y<<<64, 256, 0, stream>>>(centroids, yh, ym, yl);
  rmm_main<<<B_R / R_B, 256, 0, stream>>>(samples, mask, sd, lp, yh, ym, yl, out);
}